// Round 13
// baseline (938.460 us; speedup 1.0000x reference)
//
#include <hip/hip_runtime.h>
#include <hip/hip_cooperative_groups.h>
#include <float.h>

namespace cg = cooperative_groups;

// AttentionAgg via destination-CSR, single cooperative mega-kernel.
//   score = M @ a; smax = segmax(score,dest); ex = exp(score-smax[dest])
//   denom = segsum(ex,dest); alpha = ex/denom[dest]
//   Mv = segsum(alpha*M, dest); out = Mv[src] - alpha[rev]*M[rev]
//
// E = 800000, d = 64, N = 50000 (dim_size device scalar; hardcoded).
//
// Round-12 -> 13: ILP (r11) and bf16-gather (r12) both neutral -> kernels are
// not latency- or gather-byte-bound. Remaining suspects: 6 dispatch
// drains/ramps + zero per-kernel visibility (reset fills own the top-5).
// Fix both: ONE cooperative kernel, grid.sync() between phases, grid-stride
// work mapping, occupancy-sized grid. f32 everywhere (r9 verified bodies).
// Full 6-kernel fallback if cooperative launch is unavailable.

#define THREADS 256

typedef float f32x4 __attribute__((ext_vector_type(4)));

// ---------------------------------------------------------------------------
// Shared phase bodies (verified in round 9).

__device__ __forceinline__ void score_fill_edge(
    const float4* __restrict__ M4, const float4* __restrict__ a4,
    const int* __restrict__ dest, int* __restrict__ cursor,
    int* __restrict__ sorted_eid, float* __restrict__ sorted_score,
    int e, int sl) {
    float4 m  = M4[(size_t)e * 16 + sl];
    float4 av = a4[sl];                        // 256B, L1-resident
    float v = m.x * av.x + m.y * av.y + m.z * av.z + m.w * av.w;
    v += __shfl_xor(v, 1, 64);
    v += __shfl_xor(v, 2, 64);
    v += __shfl_xor(v, 4, 64);
    v += __shfl_xor(v, 8, 64);                 // offsets <16: in-group
    if (sl == 0) {
        int pos = atomicAdd(&cursor[dest[e]], 1);
        sorted_eid[pos]   = e;
        sorted_score[pos] = v;
    }
}

__device__ __forceinline__ void agg_node(
    const float4* __restrict__ M4, const float* __restrict__ sorted_score,
    const int* __restrict__ sorted_eid, const int* __restrict__ offsets,
    const int* __restrict__ counts, float4* __restrict__ Mv4,
    float* __restrict__ alpha, int n, int lane) {
    int beg = offsets[n];
    int deg = counts[n];
    int end = beg + deg;
    int grp = lane >> 4;
    int sl  = lane & 15;
    float4 acc = make_float4(0.f, 0.f, 0.f, 0.f);

    if (deg <= 64) {
        int   eid = 0;
        float sc  = -FLT_MAX;
        if (lane < deg) {
            eid = sorted_eid[beg + lane];      // coalesced
            sc  = sorted_score[beg + lane];    // coalesced
        }
        float m = sc;
        #pragma unroll
        for (int off = 32; off; off >>= 1)
            m = fmaxf(m, __shfl_xor(m, off, 64));
        float exr = (lane < deg) ? expf(sc - m) : 0.f;
        float ds  = exr;
        #pragma unroll
        for (int off = 32; off; off >>= 1)
            ds += __shfl_xor(ds, off, 64);
        float inv = ds > 0.f ? 1.0f / ds : 0.0f;
        if (lane < deg) alpha[eid] = exr * inv;
        // wave-uniform trip count (round-5 lesson: shfl src must be active)
        int iters = (deg + 3) >> 2;
        for (int k = 0; k < iters; ++k) {
            int i = grp + 4 * k;
            float ex = __shfl(exr, i, 64);
            int   e  = __shfl(eid, i, 64);
            if (i < deg) {
                float4 mm = M4[(size_t)e * 16 + sl];
                acc.x += ex * mm.x;
                acc.y += ex * mm.y;
                acc.z += ex * mm.z;
                acc.w += ex * mm.w;
            }
        }
        acc.x += __shfl_xor(acc.x, 16, 64);  acc.x += __shfl_xor(acc.x, 32, 64);
        acc.y += __shfl_xor(acc.y, 16, 64);  acc.y += __shfl_xor(acc.y, 32, 64);
        acc.z += __shfl_xor(acc.z, 16, 64);  acc.z += __shfl_xor(acc.z, 32, 64);
        acc.w += __shfl_xor(acc.w, 16, 64);  acc.w += __shfl_xor(acc.w, 32, 64);
        if (lane < 16) {
            float4 o;
            o.x = acc.x * inv; o.y = acc.y * inv;
            o.z = acc.z * inv; o.w = acc.w * inv;
            Mv4[(size_t)n * 16 + lane] = o;
        }
    } else {
        float m = -FLT_MAX;
        for (int i = beg + lane; i < end; i += 64)
            m = fmaxf(m, sorted_score[i]);
        #pragma unroll
        for (int off = 32; off; off >>= 1)
            m = fmaxf(m, __shfl_xor(m, off, 64));
        float dsum = 0.f;
        for (int i = beg + grp; i < end; i += 4) {
            int e = sorted_eid[i];
            float ex = expf(sorted_score[i] - m);
            if (sl == 0) dsum += ex;
            float4 mm = M4[(size_t)e * 16 + sl];
            acc.x += ex * mm.x;
            acc.y += ex * mm.y;
            acc.z += ex * mm.z;
            acc.w += ex * mm.w;
        }
        dsum += __shfl_xor(dsum, 16, 64);
        dsum += __shfl_xor(dsum, 32, 64);
        float dtot = __shfl(dsum, 0, 64);
        float inv = dtot > 0.f ? 1.0f / dtot : 0.0f;
        for (int i = beg + lane; i < end; i += 64)
            alpha[sorted_eid[i]] = expf(sorted_score[i] - m) * inv;
        acc.x += __shfl_xor(acc.x, 16, 64);  acc.x += __shfl_xor(acc.x, 32, 64);
        acc.y += __shfl_xor(acc.y, 16, 64);  acc.y += __shfl_xor(acc.y, 32, 64);
        acc.z += __shfl_xor(acc.z, 16, 64);  acc.z += __shfl_xor(acc.z, 32, 64);
        acc.w += __shfl_xor(acc.w, 16, 64);  acc.w += __shfl_xor(acc.w, 32, 64);
        if (lane < 16) {
            float4 o;
            o.x = acc.x * inv; o.y = acc.y * inv;
            o.z = acc.z * inv; o.w = acc.w * inv;
            Mv4[(size_t)n * 16 + lane] = o;
        }
    }
}

__device__ __forceinline__ void out_edge(
    const float4* __restrict__ M4, const float4* __restrict__ Mv4,
    const float* __restrict__ alpha, const int* __restrict__ src,
    const int* __restrict__ rev, f32x4* __restrict__ out4,
    int e, int sl) {
    int s    = src[e];
    int r    = rev[e];
    float al = alpha[r];
    float4 mv = Mv4[(size_t)s * 16 + sl];
    float4 mr = M4[(size_t)r * 16 + sl];
    f32x4 o;
    o.x = mv.x - al * mr.x;
    o.y = mv.y - al * mr.y;
    o.z = mv.z - al * mr.z;
    o.w = mv.w - al * mr.w;
    __builtin_nontemporal_store(o, &out4[(size_t)e * 16 + sl]);
}

// ---------------------------------------------------------------------------
// Mega-kernel: all 6 phases with grid.sync() between them.
struct Params {
    const float4* M4; const float4* a4;
    const int* src; const int* dest; const int* rev;
    int* counts; int* total; int* offsets; int* cursor;
    int* sorted_eid; float* sorted_score;
    float4* Mv4; float* alpha; f32x4* out4;
    int E; int N;
};

__global__ __launch_bounds__(THREADS)
void k_mega(Params p) {
    cg::grid_group grid = cg::this_grid();
    const int tid  = blockIdx.x * blockDim.x + threadIdx.x;
    const int nthr = gridDim.x * blockDim.x;
    const int lane = threadIdx.x & 63;

    // P0: zero counts[N] + total (contiguous N+4 ints)
    {
        int n4 = (p.N + 4) >> 2;
        int4* c4 = (int4*)p.counts;
        for (int i = tid; i < n4; i += nthr) c4[i] = make_int4(0, 0, 0, 0);
    }
    grid.sync();

    // P1: histogram of dest
    for (int e = tid; e < p.E; e += nthr) atomicAdd(&p.counts[p.dest[e]], 1);
    grid.sync();

    // P2: range alloc (wave prefix + one atomicAdd per 64-chunk)
    {
        int wid = tid >> 6;
        int nw  = nthr >> 6;
        for (int base = wid * 64; base < p.N; base += nw * 64) {
            int n = base + lane;
            int c = (n < p.N) ? p.counts[n] : 0;
            int x = c;
            #pragma unroll
            for (int off = 1; off < 64; off <<= 1) {
                int y = __shfl_up(x, off, 64);
                if (lane >= off) x += y;
            }
            int wsum = __shfl(x, 63, 64);
            int b = 0;
            if (lane == 63) b = atomicAdd(p.total, wsum);
            b = __shfl(b, 63, 64);
            if (n < p.N) {
                int my = b + x - c;
                p.offsets[n] = my;
                p.cursor[n]  = my;
            }
        }
    }
    grid.sync();

    // P3: score + CSR fill (16 lanes/edge)
    {
        int g0 = tid >> 4, sl = tid & 15, ng = nthr >> 4;
        for (int e = g0; e < p.E; e += ng)
            score_fill_edge(p.M4, p.a4, p.dest, p.cursor,
                            p.sorted_eid, p.sorted_score, e, sl);
    }
    grid.sync();

    // P4: aggregate (wave per node)
    {
        int wid = tid >> 6, nw = nthr >> 6;
        for (int n = wid; n < p.N; n += nw)
            agg_node(p.M4, p.sorted_score, p.sorted_eid, p.offsets, p.counts,
                     p.Mv4, p.alpha, n, lane);
    }
    grid.sync();

    // P5: out (16 lanes/edge)
    {
        int g0 = tid >> 4, sl = tid & 15, ng = nthr >> 4;
        for (int e = g0; e < p.E; e += ng)
            out_edge(p.M4, p.Mv4, p.alpha, p.src, p.rev, p.out4, e, sl);
    }
}

// ---------------------------------------------------------------------------
// Fallback pipeline (round-9 verified), used if cooperative launch fails.
__global__ void k_zero(int4* __restrict__ p, int n4) {
    int i = blockIdx.x * blockDim.x + threadIdx.x;
    if (i < n4) p[i] = make_int4(0, 0, 0, 0);
}
__global__ void k_hist(const int* __restrict__ dest,
                       int* __restrict__ counts, int E) {
    int e = blockIdx.x * blockDim.x + threadIdx.x;
    if (e >= E) return;
    atomicAdd(&counts[dest[e]], 1);
}
__global__ void k_alloc(const int* __restrict__ counts,
                        int* __restrict__ total,
                        int* __restrict__ offsets,
                        int* __restrict__ cursor, int N) {
    int n    = blockIdx.x * blockDim.x + threadIdx.x;
    int lane = threadIdx.x & 63;
    int c = (n < N) ? counts[n] : 0;
    int x = c;
    #pragma unroll
    for (int off = 1; off < 64; off <<= 1) {
        int y = __shfl_up(x, off, 64);
        if (lane >= off) x += y;
    }
    int wsum = __shfl(x, 63, 64);
    int b = 0;
    if (lane == 63) b = atomicAdd(total, wsum);
    b = __shfl(b, 63, 64);
    if (n < N) {
        int my = b + x - c;
        offsets[n] = my;
        cursor[n]  = my;
    }
}
__global__ void k_score_fill(const float4* __restrict__ M4,
                             const float4* __restrict__ a4,
                             const int* __restrict__ dest,
                             int* __restrict__ cursor,
                             int* __restrict__ sorted_eid,
                             float* __restrict__ sorted_score, int E) {
    long long gid = (long long)blockIdx.x * blockDim.x + threadIdx.x;
    int e  = (int)(gid >> 4);
    int sl = (int)(gid & 15);
    if (e >= E) return;
    score_fill_edge(M4, a4, dest, cursor, sorted_eid, sorted_score, e, sl);
}
__global__ void k_aggregate(const float4* __restrict__ M4,
                            const float* __restrict__ sorted_score,
                            const int* __restrict__ sorted_eid,
                            const int* __restrict__ offsets,
                            const int* __restrict__ counts,
                            float4* __restrict__ Mv4,
                            float* __restrict__ alpha, int N) {
    long long gid = (long long)blockIdx.x * blockDim.x + threadIdx.x;
    int n    = (int)(gid >> 6);
    int lane = (int)(gid & 63);
    if (n >= N) return;
    agg_node(M4, sorted_score, sorted_eid, offsets, counts, Mv4, alpha, n, lane);
}
__global__ void k_out(const float4* __restrict__ M4,
                      const float4* __restrict__ Mv4,
                      const float* __restrict__ alpha,
                      const int* __restrict__ src,
                      const int* __restrict__ rev,
                      f32x4* __restrict__ out4, int E) {
    long long gid = (long long)blockIdx.x * blockDim.x + threadIdx.x;
    int e  = (int)(gid >> 4);
    int sl = (int)(gid & 15);
    if (e >= E) return;
    out_edge(M4, Mv4, alpha, src, rev, out4, e, sl);
}

// ---------------------------------------------------------------------------
extern "C" void kernel_launch(void* const* d_in, const int* in_sizes, int n_in,
                              void* d_out, int out_size, void* d_ws, size_t ws_size,
                              hipStream_t stream) {
    const float* M  = (const float*)d_in[0];
    const float* a  = (const float*)d_in[1];
    const int* eidx = (const int*)d_in[2];   // [2, E] flat: src row, dest row
    const int* rev  = (const int*)d_in[3];
    const int N = 50000;
    const int E = in_sizes[3];

    // Workspace: Mv[N*64] | sorted_score[E] | alpha[E] | sorted_eid[E] |
    //            counts[N]+total[4] | offsets[N] | cursor[N]
    char* ws = (char*)d_ws;
    float* Mv           = (float*)ws; ws += (size_t)N * 64 * 4;
    float* sorted_score = (float*)ws; ws += (size_t)E * 4;
    float* alpha        = (float*)ws; ws += (size_t)E * 4;
    int*   sorted_eid   = (int*)ws;   ws += (size_t)E * 4;
    int*   counts       = (int*)ws;   ws += (size_t)(N + 4) * 4;
    int*   offsets      = (int*)ws;   ws += (size_t)N * 4;
    int*   cursor       = (int*)ws;   ws += (size_t)N * 4;
    int*   total        = counts + N;

    Params p;
    p.M4 = (const float4*)M;  p.a4 = (const float4*)a;
    p.src = eidx; p.dest = eidx + E; p.rev = rev;
    p.counts = counts; p.total = total; p.offsets = offsets; p.cursor = cursor;
    p.sorted_eid = sorted_eid; p.sorted_score = sorted_score;
    p.Mv4 = (float4*)Mv; p.alpha = alpha; p.out4 = (f32x4*)d_out;
    p.E = E; p.N = N;

    // Cooperative path: occupancy-sized grid (all blocks co-resident).
    int dev = 0;
    hipGetDevice(&dev);
    int nCU = 256;
    hipDeviceGetAttribute(&nCU, hipDeviceAttributeMultiprocessorCount, dev);
    int occ = 0;
    hipError_t oe =
        hipOccupancyMaxActiveBlocksPerMultiprocessor(&occ, k_mega, THREADS, 0);
    if (oe == hipSuccess && occ >= 1 && nCU >= 1) {
        int blocks = occ * nCU;
        void* args[] = { (void*)&p };
        hipError_t le = hipLaunchCooperativeKernel(
            (const void*)k_mega, dim3(blocks), dim3(THREADS), args, 0, stream);
        if (le == hipSuccess) return;
    }

    // Fallback: 6-kernel pipeline (round-9 verified, 259us).
    long long tE16 = (long long)E * 16;
    int blocksE16 = (int)((tE16 + THREADS - 1) / THREADS);
    int blocksE   = (E + THREADS - 1) / THREADS;
    int blocksN   = (N + THREADS - 1) / THREADS;
    int blocksN64 = (int)(((long long)N * 64 + THREADS - 1) / THREADS);
    int n4        = (N + 4) / 4;
    int blocksZ   = (n4 + THREADS - 1) / THREADS;

    k_zero<<<blocksZ, THREADS, 0, stream>>>((int4*)counts, n4);
    k_hist<<<blocksE, THREADS, 0, stream>>>(p.dest, counts, E);
    k_alloc<<<blocksN, THREADS, 0, stream>>>(counts, total, offsets, cursor, N);
    k_score_fill<<<blocksE16, THREADS, 0, stream>>>(
        p.M4, p.a4, p.dest, cursor, sorted_eid, sorted_score, E);
    k_aggregate<<<blocksN64, THREADS, 0, stream>>>(
        p.M4, sorted_score, sorted_eid, offsets, counts,
        (float4*)Mv, alpha, N);
    k_out<<<blocksE16, THREADS, 0, stream>>>(
        p.M4, (const float4*)Mv, alpha, p.src, p.rev, (f32x4*)d_out, E);
}

// Round 14
// 269.800 us; speedup vs baseline: 3.4784x; 3.4784x over previous
//
#include <hip/hip_runtime.h>
#include <float.h>

// AttentionAgg via destination-CSR (no float atomics).
//   score = M @ a; smax = segmax(score,dest); ex = exp(score-smax[dest])
//   denom = segsum(ex,dest); alpha = ex/denom[dest]
//   Mv = segsum(alpha*M, dest); out = Mv[src] - alpha[rev]*M[rev]
//
// E = 800000, d = 64, N = 50000 (dim_size device scalar; hardcoded).
//
// Round-13 -> 14: cooperative mega-kernel was 5x WORSE (grid.sync spin
// stalls: 97% occupancy, 2% VALUBusy) -> reverted to the 6-kernel pipeline.
// New lever: fold the score computation INTO k_aggregate. The aggregate
// wave already gathers every M row it needs; pass A computes dot(M[e],a)
// from that one cold gather (scores staged lane-indexed via 1KB LDS),
// pass B re-gathers the same rows hot (L1/L2/L3) for the weighted sum.
// k_score_fill collapses to k_fill (no M stream, -205MB HBM);
// sorted_score[] deleted. __syncthreads hoisted outside divergent branches.

#define THREADS 256

typedef float f32x4 __attribute__((ext_vector_type(4)));

// ---------------------------------------------------------------------------
// K0: zero counts[N] + total counter (N+4 ints, multiple of 4).
__global__ void k_zero(int4* __restrict__ p, int n4) {
    int i = blockIdx.x * blockDim.x + threadIdx.x;
    if (i < n4) p[i] = make_int4(0, 0, 0, 0);
}

// ---------------------------------------------------------------------------
// K1: histogram of dest (reads 3.2MB only).
__global__ void k_hist(const int* __restrict__ dest,
                       int* __restrict__ counts, int E) {
    int e = blockIdx.x * blockDim.x + threadIdx.x;
    if (e >= E) return;
    atomicAdd(&counts[dest[e]], 1);
}

// ---------------------------------------------------------------------------
// K2: range allocation. Wave-level exclusive prefix over counts + one
// atomicAdd(total) per wave -> offsets[n], cursor[n].
__global__ void k_alloc(const int* __restrict__ counts,
                        int* __restrict__ total,
                        int* __restrict__ offsets,
                        int* __restrict__ cursor,
                        int N) {
    int n    = blockIdx.x * blockDim.x + threadIdx.x;
    int lane = threadIdx.x & 63;
    int c = (n < N) ? counts[n] : 0;
    int x = c;
    #pragma unroll
    for (int off = 1; off < 64; off <<= 1) {
        int y = __shfl_up(x, off, 64);
        if (lane >= off) x += y;
    }
    int wsum = __shfl(x, 63, 64);
    int base = 0;
    if (lane == 63) base = atomicAdd(total, wsum);
    base = __shfl(base, 63, 64);
    if (n < N) {
        int my = base + x - c;                 // exclusive position
        offsets[n] = my;
        cursor[n]  = my;
    }
}

// ---------------------------------------------------------------------------
// K3: bucket fill (thread per edge; no M traffic).
__global__ void k_fill(const int* __restrict__ dest,
                       int* __restrict__ cursor,
                       int* __restrict__ sorted_eid,
                       int E) {
    int e = blockIdx.x * blockDim.x + threadIdx.x;
    if (e >= E) return;
    int pos = atomicAdd(&cursor[dest[e]], 1);
    sorted_eid[pos] = e;
}

// ---------------------------------------------------------------------------
// K4: one wave per node; computes scores AND softmax AND Mv AND alpha.
// Fast path (deg<=64):
//   pass A: grouped row gather (cold, coalesced 256B rows); dot with a;
//           4-shfl reduce in 16-group; stage score to LDS (lane-indexed).
//   softmax: per-lane max/exp/sum shfl reductions; alpha[eid] = ex*inv.
//   pass B: re-gather same rows (cache-hot) with shfl-broadcast weights.
// Slow path (deg>64, ~never at mean deg 16): per-lane row-walk scores
// staged via alpha[] as scratch, then classic two-pass.
// __syncthreads() is OUTSIDE all divergent branches (barrier uniformity).
__global__ void k_aggregate(const float4* __restrict__ M4,
                            const float4* __restrict__ a4,
                            const int* __restrict__ sorted_eid,
                            const int* __restrict__ offsets,
                            const int* __restrict__ counts,
                            float4* __restrict__ Mv4,
                            float* __restrict__ alpha,
                            int N) {
    __shared__ float s_sc[THREADS / 64][64];
    long long gid = (long long)blockIdx.x * blockDim.x + threadIdx.x;
    int n     = (int)(gid >> 6);
    int lane  = (int)(gid & 63);
    int wslot = threadIdx.x >> 6;
    int grp   = lane >> 4;
    int sl    = lane & 15;

    bool valid = n < N;
    int beg = 0, deg = 0;
    if (valid) { beg = offsets[n]; deg = counts[n]; }
    bool fast = valid && (deg <= 64);

    float4 avsl = a4[sl];                      // lane's 16B slice of a
    int eid = 0;

    if (fast) {
        if (lane < deg) eid = sorted_eid[beg + lane];   // coalesced
        int iters = (deg + 3) >> 2;            // wave-uniform (r5 lesson)
        for (int k = 0; k < iters; ++k) {
            int i = grp + 4 * k;
            int e = __shfl(eid, i, 64);        // all lanes active
            float p = 0.f;
            if (i < deg) {
                float4 mm = M4[(size_t)e * 16 + sl];    // COLD gather
                p = mm.x * avsl.x + mm.y * avsl.y
                  + mm.z * avsl.z + mm.w * avsl.w;
            }
            p += __shfl_xor(p, 1, 64);
            p += __shfl_xor(p, 2, 64);
            p += __shfl_xor(p, 4, 64);
            p += __shfl_xor(p, 8, 64);
            if (sl == 0 && i < deg) s_sc[wslot][i] = p;
        }
    }
    __syncthreads();                           // uniform: every thread
    if (!valid) return;

    float4 acc = make_float4(0.f, 0.f, 0.f, 0.f);

    if (fast) {
        float sc = (lane < deg) ? s_sc[wslot][lane] : -FLT_MAX;
        float m = sc;
        #pragma unroll
        for (int off = 32; off; off >>= 1)
            m = fmaxf(m, __shfl_xor(m, off, 64));
        float exr = (lane < deg) ? expf(sc - m) : 0.f;
        float ds  = exr;
        #pragma unroll
        for (int off = 32; off; off >>= 1)
            ds += __shfl_xor(ds, off, 64);
        float inv = ds > 0.f ? 1.0f / ds : 0.0f;
        if (lane < deg) alpha[eid] = exr * inv;
        int iters = (deg + 3) >> 2;
        for (int k = 0; k < iters; ++k) {
            int i = grp + 4 * k;
            float ex = __shfl(exr, i, 64);
            int   e  = __shfl(eid, i, 64);
            if (i < deg) {
                float4 mm = M4[(size_t)e * 16 + sl];    // HOT re-gather
                acc.x += ex * mm.x;
                acc.y += ex * mm.y;
                acc.z += ex * mm.z;
                acc.w += ex * mm.w;
            }
        }
        acc.x += __shfl_xor(acc.x, 16, 64);  acc.x += __shfl_xor(acc.x, 32, 64);
        acc.y += __shfl_xor(acc.y, 16, 64);  acc.y += __shfl_xor(acc.y, 32, 64);
        acc.z += __shfl_xor(acc.z, 16, 64);  acc.z += __shfl_xor(acc.z, 32, 64);
        acc.w += __shfl_xor(acc.w, 16, 64);  acc.w += __shfl_xor(acc.w, 32, 64);
        if (lane < 16) {
            float4 o;
            o.x = acc.x * inv; o.y = acc.y * inv;
            o.z = acc.z * inv; o.w = acc.w * inv;
            Mv4[(size_t)n * 16 + lane] = o;
        }
    } else {
        // Slow path: per-lane row-walk scores, staged via alpha[] scratch.
        int end = beg + deg;
        float m = -FLT_MAX;
        for (int i = beg + lane; i < end; i += 64) {
            int e = sorted_eid[i];
            const float4* row = M4 + (size_t)e * 16;
            float s = 0.f;
            #pragma unroll
            for (int j = 0; j < 16; ++j) {
                float4 mm = row[j];
                float4 av = a4[j];
                s += mm.x * av.x + mm.y * av.y + mm.z * av.z + mm.w * av.w;
            }
            alpha[e] = s;                      // scratch: raw score
            m = fmaxf(m, s);
        }
        #pragma unroll
        for (int off = 32; off; off >>= 1)
            m = fmaxf(m, __shfl_xor(m, off, 64));
        float dsum = 0.f;
        for (int i = beg + grp; i < end; i += 4) {
            int e = sorted_eid[i];
            float ex = expf(alpha[e] - m);
            if (sl == 0) dsum += ex;
            float4 mm = M4[(size_t)e * 16 + sl];
            acc.x += ex * mm.x;
            acc.y += ex * mm.y;
            acc.z += ex * mm.z;
            acc.w += ex * mm.w;
        }
        dsum += __shfl_xor(dsum, 16, 64);
        dsum += __shfl_xor(dsum, 32, 64);
        float dtot = __shfl(dsum, 0, 64);
        float inv = dtot > 0.f ? 1.0f / dtot : 0.0f;
        for (int i = beg + lane; i < end; i += 64) {
            int e = sorted_eid[i];
            alpha[e] = expf(alpha[e] - m) * inv;   // overwrite scratch
        }
        acc.x += __shfl_xor(acc.x, 16, 64);  acc.x += __shfl_xor(acc.x, 32, 64);
        acc.y += __shfl_xor(acc.y, 16, 64);  acc.y += __shfl_xor(acc.y, 32, 64);
        acc.z += __shfl_xor(acc.z, 16, 64);  acc.z += __shfl_xor(acc.z, 32, 64);
        acc.w += __shfl_xor(acc.w, 16, 64);  acc.w += __shfl_xor(acc.w, 32, 64);
        if (lane < 16) {
            float4 o;
            o.x = acc.x * inv; o.y = acc.y * inv;
            o.z = acc.z * inv; o.w = acc.w * inv;
            Mv4[(size_t)n * 16 + lane] = o;
        }
    }
}

// ---------------------------------------------------------------------------
// K5: 16 lanes/edge. out = Mv[src] - alpha[rev] * M[rev]. Per-lane
// same-address scalar loads (HW broadcast). Nontemporal store so the 205MB
// out-stream doesn't evict the gathered M rows from L3.
__global__ void k_out(const float4* __restrict__ M4,
                      const float4* __restrict__ Mv4,
                      const float* __restrict__ alpha,
                      const int* __restrict__ src,
                      const int* __restrict__ rev,
                      f32x4* __restrict__ out4,
                      int E) {
    long long gid = (long long)blockIdx.x * blockDim.x + threadIdx.x;
    int e  = (int)(gid >> 4);
    int sl = (int)(gid & 15);
    if (e >= E) return;
    int s    = src[e];
    int r    = rev[e];
    float al = alpha[r];
    float4 mv = Mv4[(size_t)s * 16 + sl];
    float4 mr = M4[(size_t)r * 16 + sl];
    f32x4 o;
    o.x = mv.x - al * mr.x;
    o.y = mv.y - al * mr.y;
    o.z = mv.z - al * mr.z;
    o.w = mv.w - al * mr.w;
    __builtin_nontemporal_store(o, &out4[(size_t)e * 16 + sl]);
}

// ---------------------------------------------------------------------------
extern "C" void kernel_launch(void* const* d_in, const int* in_sizes, int n_in,
                              void* d_out, int out_size, void* d_ws, size_t ws_size,
                              hipStream_t stream) {
    const float* M  = (const float*)d_in[0];
    const float* a  = (const float*)d_in[1];
    const int* eidx = (const int*)d_in[2];   // [2, E] flat: src row, dest row
    const int* rev  = (const int*)d_in[3];
    const int N = 50000;
    const int E = in_sizes[3];

    const int* src  = eidx;
    const int* dest = eidx + E;

    // Workspace: Mv[N*64] | alpha[E] | sorted_eid[E] |
    //            counts[N]+total[4] | offsets[N] | cursor[N]
    char* ws = (char*)d_ws;
    float* Mv         = (float*)ws; ws += (size_t)N * 64 * 4;
    float* alpha      = (float*)ws; ws += (size_t)E * 4;
    int*   sorted_eid = (int*)ws;   ws += (size_t)E * 4;
    int*   counts     = (int*)ws;   ws += (size_t)(N + 4) * 4;  // +total
    int*   offsets    = (int*)ws;   ws += (size_t)N * 4;
    int*   cursor     = (int*)ws;   ws += (size_t)N * 4;
    int*   total      = counts + N;

    long long tE16 = (long long)E * 16;
    int blocksE16 = (int)((tE16 + THREADS - 1) / THREADS);
    int blocksE   = (E + THREADS - 1) / THREADS;
    int blocksN   = (N + THREADS - 1) / THREADS;
    int blocksN64 = (int)(((long long)N * 64 + THREADS - 1) / THREADS);
    int n4        = (N + 4) / 4;               // counts + total
    int blocksZ   = (n4 + THREADS - 1) / THREADS;

    k_zero<<<blocksZ, THREADS, 0, stream>>>((int4*)counts, n4);
    k_hist<<<blocksE, THREADS, 0, stream>>>(dest, counts, E);
    k_alloc<<<blocksN, THREADS, 0, stream>>>(counts, total, offsets, cursor, N);
    k_fill<<<blocksE, THREADS, 0, stream>>>(dest, cursor, sorted_eid, E);
    k_aggregate<<<blocksN64, THREADS, 0, stream>>>(
        (const float4*)M, (const float4*)a, sorted_eid, offsets, counts,
        (float4*)Mv, alpha, N);
    k_out<<<blocksE16, THREADS, 0, stream>>>(
        (const float4*)M, (const float4*)Mv, alpha, src, rev,
        (f32x4*)d_out, E);
}